// Round 12
// baseline (401.952 us; speedup 1.0000x reference)
//
#include <hip/hip_runtime.h>

typedef unsigned short u16;
typedef unsigned int u32;
typedef __attribute__((ext_vector_type(4))) float f32x4;
typedef __attribute__((ext_vector_type(8))) short s16x8;
typedef __attribute__((ext_vector_type(4))) u16 u16x4;
typedef __attribute__((ext_vector_type(2))) u32 u32x2;

#define L2E 1.4426950408889634f
#define QSCALE 0.18033688011112042f /* (1/8) * log2(e) */
#define NBLK 512u

__device__ __forceinline__ u16 f2bf(float f) {  // RNE
    union { float f; u32 i; } v; v.f = f;
    return (u16)((v.i + 0x7fffu + ((v.i >> 16) & 1u)) >> 16);
}
// pack hi16(a) | hi16(b)<<16 — single v_perm_b32 (bf16 truncation)
__device__ __forceinline__ u32 pack_hi(float a, float b) {
    union { float f; u32 i; } x, y; x.f = a; y.f = b;
    return __builtin_amdgcn_perm(y.i, x.i, 0x07060302u);
}
__device__ __forceinline__ float bflo(u32 w) {
    union { u32 i; float f; } v; v.i = w << 16; return v.f;
}
__device__ __forceinline__ float bfhi(u32 w) {
    union { u32 i; float f; } v; v.i = w & 0xFFFF0000u; return v.f;
}

// async global->LDS, 16B per lane; LDS dest = wave-uniform base + lane*16
__device__ __forceinline__ void gl2lds16(const u16* g, u16* l) {
    __builtin_amdgcn_global_load_lds(
        (const __attribute__((address_space(1))) void*)g,
        (__attribute__((address_space(3))) void*)l, 16, 0, 0);
}

// Manual grid barrier: all 512 blocks are co-resident (2/CU by construction:
// 64KB LDS -> 2 blocks/CU of the 160KB; launch_bounds(256,2) caps VGPR<=256).
// cnt is zeroed by hipMemsetAsync before launch; single-use per barrier.
// Polling uses atomicAdd(cnt,0) — device-scope coherent read (a plain load
// could spin forever on a stale per-XCD L2 line).
__device__ __forceinline__ void grid_barrier(u32* cnt) {
    __syncthreads();
    if (threadIdx.x == 0) {
        __threadfence();                      // release: my writes visible
        atomicAdd(cnt, 1u);
        while (atomicAdd(cnt, 0u) < NBLK) __builtin_amdgcn_s_sleep(8);
        __threadfence();                      // acquire: others' writes visible
    }
    __syncthreads();
}

// ---------------------------------------------------------------------------
// GEMM core, M=64 tiles, bf16 both operands, double-buffered LDS
// (R7/R8-verified). As: 2*2048 u16, Bs: 2*4096 u16.
// ---------------------------------------------------------------------------
__device__ __forceinline__ void gemm_core_m64(
    const u16* __restrict__ A, const u16* __restrict__ Bw,
    int m0, int n0, u16* As, u16* Bs, f32x4 acc[2][4])
{
    const int tid = threadIdx.x;
    const int lane = tid & 63, w = tid >> 6;
    const int wm = w & 1, wn = w >> 1;
    const int l16 = lane & 15, quad = lane >> 4;
    const int srow = (lane >> 2), sch = (lane & 3) * 8;
    const f32x4 vzero = {0.f, 0.f, 0.f, 0.f};
#pragma unroll
    for (int i = 0; i < 2; ++i)
#pragma unroll
        for (int j = 0; j < 4; ++j) acc[i][j] = vzero;

    gl2lds16(&A[(size_t)(m0 + w * 16 + srow) * 512 + sch], &As[w * 512]);
#pragma unroll
    for (int j = 0; j < 2; ++j) {
        int row = w * 32 + j * 16 + srow;
        gl2lds16(&Bw[(size_t)(n0 + row) * 512 + sch], &Bs[w * 1024 + j * 512]);
    }
    for (int kt = 0; kt < 16; ++kt) {
        __syncthreads();
        const int curA = (kt & 1) * 2048, curB = (kt & 1) * 4096;
        if (kt < 15) {
            const int nxtA = 2048 - curA, nxtB = 4096 - curB;
            gl2lds16(&A[(size_t)(m0 + w * 16 + srow) * 512 + (kt + 1) * 32 + sch],
                     &As[nxtA + w * 512]);
#pragma unroll
            for (int j = 0; j < 2; ++j) {
                int row = w * 32 + j * 16 + srow;
                gl2lds16(&Bw[(size_t)(n0 + row) * 512 + (kt + 1) * 32 + sch],
                         &Bs[nxtB + w * 1024 + j * 512]);
            }
        }
        s16x8 af[2], bfr[4];
#pragma unroll
        for (int mt = 0; mt < 2; ++mt)
            af[mt] = *(const s16x8*)&As[curA + (wm * 32 + mt * 16 + l16) * 32 + quad * 8];
#pragma unroll
        for (int nt = 0; nt < 4; ++nt)
            bfr[nt] = *(const s16x8*)&Bs[curB + (wn * 64 + nt * 16 + l16) * 32 + quad * 8];
#pragma unroll
        for (int mt = 0; mt < 2; ++mt)
#pragma unroll
            for (int nt = 0; nt < 4; ++nt)
                acc[mt][nt] = __builtin_amdgcn_mfma_f32_16x16x32_bf16(
                    af[mt], bfr[nt], acc[mt][nt], 0, 0, 0);
    }
}

// ---------------------------------------------------------------------------
// Mega-kernel: 512 blocks x 256 threads, exactly 2 blocks/CU co-resident.
// Phase A: conv (fp32->bf16, grid-stride) + LG gate precompute.
// Phase B: QKV projection, 1536 m64-tiles = exactly 3 per block.
// Phase C: attention (R8-verified body; bid -> (qg, head, b)).
// Phase D: output projection, 512 m64-tiles = 1 per block.
// Manual atomic grid barriers replace 3 kernel-launch boundaries.
// ---------------------------------------------------------------------------
__global__ __launch_bounds__(256, 2) void mega_kernel(
    const float* __restrict__ Qin, const float* __restrict__ KVin,
    const float* __restrict__ SC,
    const float* __restrict__ Wq, const float* __restrict__ bq,
    const float* __restrict__ Wk, const float* __restrict__ bk,
    const float* __restrict__ Wv, const float* __restrict__ bv,
    const float* __restrict__ gw, const float* __restrict__ gb,
    const float* __restrict__ Wo, const float* __restrict__ bo,
    float* __restrict__ out, u16* __restrict__ ws, u32* __restrict__ bar)
{
    __shared__ __align__(16) u16 smem[32768];   // 64 KB, re-used per phase

    // ws layout (u16 units): conv 9.4M | Qh/Kh/Vt/Ob 4.2M each | LGx 16.8M
    u16* convb = ws;
    u16* cQin = convb;
    u16* cKV  = convb + 4194304;
    u16* cW   = convb + 8388608;       // Wq,Wk,Wv,Wo each 262,144
    u16* Qh   = convb + 9437184;
    u16* Kh   = Qh + 4194304;
    u16* Vt   = Kh + 4194304;
    u16* Ob   = Vt + 4194304;
    u16* LGx  = Ob + 4194304;

    const int tid = threadIdx.x;
    const int bid = blockIdx.x;
    const int lane = tid & 63, w = tid >> 6;
    const int l16 = lane & 15, quad = lane >> 4;

    // ---------------- Phase A: conv + lg ----------------
    for (int i = bid; i < 9216; i += 512) {
        int e = (i * 256 + tid) * 4;
        const float* src; int off;
        if      (e < 4194304) { src = Qin;  off = e; }
        else if (e < 8388608) { src = KVin; off = e - 4194304; }
        else if (e < 8650752) { src = Wq;   off = e - 8388608; }
        else if (e < 8912896) { src = Wk;   off = e - 8650752; }
        else if (e < 9175040) { src = Wv;   off = e - 8912896; }
        else                  { src = Wo;   off = e - 9175040; }
        f32x4 f = *(const f32x4*)(src + off);
        u16x4 o;
#pragma unroll
        for (int j = 0; j < 4; ++j) o[j] = f2bf(f[j]);
        *(u16x4*)(convb + e) = o;
    }
    {
        const float tA = -gw[0] * L2E, tB = -gb[0] * L2E;
        for (int vb = bid; vb < 4096; vb += 512) {
            const int flat = vb * 256 + tid;
            const int ll = flat & 63;
            const int kt   = (flat >> 6) & 31;
            const int t16  = (flat >> 11) & 127;
            const int b    = flat >> 18;
            const int l16l = ll & 15, qd = ll >> 4;
            const float* row = SC + ((size_t)b * 2048 + t16 * 16 + l16l) * 2048
                                  + kt * 64 + qd * 4;
            __align__(16) u16 tmp[16];
#pragma unroll
            for (int kk = 0; kk < 4; ++kk) {
                f32x4 x = *(const f32x4*)(row + kk * 16);
#pragma unroll
                for (int reg = 0; reg < 4; ++reg) {
                    float g = __builtin_amdgcn_rcpf(
                        1.0f + __builtin_amdgcn_exp2f(tA * x[reg] + tB)) + 1e-8f;
                    tmp[kk * 4 + reg] = f2bf(__builtin_amdgcn_logf(g));  // log2
                }
            }
            u16* d = LGx + (size_t)flat * 16;
            *(uint4*)d       = *(uint4*)tmp;
            *(uint4*)(d + 8) = *(uint4*)(tmp + 8);
        }
    }
    grid_barrier(bar + 0);

    // ---------------- Phase B: QKV projection (3 m64-tiles/block) ----------
    {
        u16* As = smem;            // 2*2048 u16
        u16* Bs = smem + 4096;     // 2*4096 u16
        const int n0 = (bid & 3) * 128;
        const int m0 = (bid >> 2) * 64;
        const int wm = w & 1, wn = w >> 1;
#pragma unroll 1
        for (int job = 0; job < 3; ++job) {
            const u16* A = (job == 0) ? cQin : cKV;
            const u16* W = cW + (size_t)job * 262144;
            const float* bias = (job == 0) ? bq : (job == 1 ? bk : bv);
            f32x4 acc[2][4];
            gemm_core_m64(A, W, m0, n0, As, Bs, acc);
#pragma unroll
            for (int nt = 0; nt < 4; ++nt) {
                int j = n0 + wn * 64 + nt * 16 + l16;
                float bj = bias[j];
                int h = j >> 6, d = j & 63;
#pragma unroll
                for (int mt = 0; mt < 2; ++mt) {
                    int trow = m0 + wm * 32 + mt * 16 + quad * 4;
                    int bb = trow >> 11, nn = trow & 2047;
                    int bh = bb * 8 + h;
                    if (job == 2) {
                        u16x4 pv;
#pragma unroll
                        for (int reg = 0; reg < 4; ++reg)
                            pv[reg] = f2bf(acc[mt][nt][reg] + bj);
                        *(u16x4*)&Vt[(size_t)(bh * 64 + d) * 2048 + nn] = pv;
                    } else if (job == 0) {
#pragma unroll
                        for (int reg = 0; reg < 4; ++reg)
                            Qh[(size_t)(bh * 2048 + nn + reg) * 64 + d] =
                                f2bf((acc[mt][nt][reg] + bj) * QSCALE);
                    } else {
#pragma unroll
                        for (int reg = 0; reg < 4; ++reg)
                            Kh[(size_t)(bh * 2048 + nn + reg) * 64 + d] =
                                f2bf(acc[mt][nt][reg] + bj);
                    }
                }
            }
            __syncthreads();   // As/Bs quiesce before next job's prologue
        }
    }
    grid_barrier(bar + 64);

    // ---------------- Phase C: attention (R8-verified body) ----------------
    {
        u16* Ksm = smem;            // 2 bufs x 8192 u16
        u16* Vsm = smem + 16384;    // 2 bufs x 8192 u16
        const int b = bid >> 7, head = (bid >> 4) & 7, qg = bid & 15;
        const int bh = b * 8 + head;
        const int q0a = qg * 128 + w * 32, q0b = q0a + 16;
        const int t16a = qg * 8 + w * 2;
        const u16* Qp = Qh + (size_t)bh * 131072;
        const u16* Kp = Kh + (size_t)bh * 131072;
        const u16* Vp = Vt + (size_t)bh * 131072;
        const u16* lgPa = LGx + ((size_t)((b * 128 + t16a) * 32) * 64 + lane) * 16;
        const u16* lgPb = LGx + ((size_t)((b * 128 + t16a + 1) * 32) * 64 + lane) * 16;
        const f32x4 vzero = {0.f, 0.f, 0.f, 0.f};
        const s16x8 ones = {0x3F80, 0x3F80, 0x3F80, 0x3F80,
                            0x3F80, 0x3F80, 0x3F80, 0x3F80};  // bf16 1.0 x8

        const int s3 = l16 & 7, s2x = s3 & 3, s4x = s3 & 4;
        const int qsw = (quad ^ s2x) * 8;
        const int rb0 = l16 * 64 + qsw + s4x * 8;          // kc even
        const int rb1 = l16 * 64 + qsw + (4 ^ s4x) * 8;    // kc odd
        const u16* KbL = Ksm;
        const u16* VbL = Vsm;

        const int sr = lane >> 3, c8 = lane & 7;           // 8 rows x 8 chunks
        const bool isK = (w < 2);
        const int hv = w & 1;
        const u16* sgq = isK
            ? (Kp + (size_t)(hv * 64 + sr) * 64 + (c8 ^ sr) * 8)
            : (Vp + (size_t)sr * 2048 + hv * 64 + (c8 ^ sr) * 8);
        const size_t slabAdv = isK ? 512 : 16384;  // +8 rows (u16)
        const size_t tileAdv = isK ? 8192 : 128;   // next 128-key tile (u16)
        u16* sdb = isK ? (Ksm + hv * 4096) : (Vsm + hv * 4096);

        s16x8 qfa0 = *(const s16x8*)&Qp[(size_t)(q0a + l16) * 64 + quad * 8];
        s16x8 qfa1 = *(const s16x8*)&Qp[(size_t)(q0a + l16) * 64 + 32 + quad * 8];
        s16x8 qfb0 = *(const s16x8*)&Qp[(size_t)(q0b + l16) * 64 + quad * 8];
        s16x8 qfb1 = *(const s16x8*)&Qp[(size_t)(q0b + l16) * 64 + 32 + quad * 8];
        f32x4 oA[4], oB[4], laccA = vzero, laccB = vzero;
#pragma unroll
        for (int dn = 0; dn < 4; ++dn) { oA[dn] = vzero; oB[dn] = vzero; }

#pragma unroll
        for (int j = 0; j < 8; ++j)
            gl2lds16(sgq + (size_t)j * slabAdv, sdb + j * 512);
        sgq += tileAdv;
        uint4 lga0 = *(const uint4*)lgPa;
        uint4 lga1 = *(const uint4*)(lgPa + 8);
        uint4 lga2 = *(const uint4*)(lgPa + 1024);
        uint4 lga3 = *(const uint4*)(lgPa + 1032);
        uint4 lgb0 = *(const uint4*)lgPb;
        uint4 lgb1 = *(const uint4*)(lgPb + 8);
        uint4 lgb2 = *(const uint4*)(lgPb + 1024);
        uint4 lgb3 = *(const uint4*)(lgPb + 1032);
        lgPa += 2048; lgPb += 2048;

        for (int kt = 0; kt < 16; ++kt) {
            __syncthreads();  // tile[kt&1] staged, previous reads done
            const int bo = (kt & 1) * 8192;
            if (kt < 15) {    // prefetch tile kt+1 into the other buffer
                u16* dd = sdb + (8192 - bo);
#pragma unroll
                for (int j = 0; j < 8; ++j)
                    gl2lds16(sgq + (size_t)j * slabAdv, dd + j * 512);
                sgq += tileAdv;
            }
            __builtin_amdgcn_s_setprio(1);
            u32 PwA8[8][2], PwB8[8][2];
            {
                const u32 wda[8] = {lga0.x, lga0.y, lga0.z, lga0.w,
                                    lga1.x, lga1.y, lga1.z, lga1.w};
                const u32 wdb[8] = {lgb0.x, lgb0.y, lgb0.z, lgb0.w,
                                    lgb1.x, lgb1.y, lgb1.z, lgb1.w};
#pragma unroll
                for (int kk = 0; kk < 4; ++kk) {
                    s16x8 ka = *(const s16x8*)(KbL + bo + rb0 + kk * 1024);
                    s16x8 kb = *(const s16x8*)(KbL + bo + rb1 + kk * 1024);
                    f32x4 ci;
                    ci[0] = bflo(wda[kk * 2]);     ci[1] = bfhi(wda[kk * 2]);
                    ci[2] = bflo(wda[kk * 2 + 1]); ci[3] = bfhi(wda[kk * 2 + 1]);
                    f32x4 s = __builtin_amdgcn_mfma_f32_16x16x32_bf16(ka, qfa0, ci, 0, 0, 0);
                    s = __builtin_amdgcn_mfma_f32_16x16x32_bf16(kb, qfa1, s, 0, 0, 0);
                    f32x4 cj;
                    cj[0] = bflo(wdb[kk * 2]);     cj[1] = bfhi(wdb[kk * 2]);
                    cj[2] = bflo(wdb[kk * 2 + 1]); cj[3] = bfhi(wdb[kk * 2 + 1]);
                    f32x4 t = __builtin_amdgcn_mfma_f32_16x16x32_bf16(ka, qfb0, cj, 0, 0, 0);
                    t = __builtin_amdgcn_mfma_f32_16x16x32_bf16(kb, qfb1, t, 0, 0, 0);
                    PwA8[kk][0] = pack_hi(__builtin_amdgcn_exp2f(s[0]),
                                          __builtin_amdgcn_exp2f(s[1]));
                    PwA8[kk][1] = pack_hi(__builtin_amdgcn_exp2f(s[2]),
                                          __builtin_amdgcn_exp2f(s[3]));
                    PwB8[kk][0] = pack_hi(__builtin_amdgcn_exp2f(t[0]),
                                          __builtin_amdgcn_exp2f(t[1]));
                    PwB8[kk][1] = pack_hi(__builtin_amdgcn_exp2f(t[2]),
                                          __builtin_amdgcn_exp2f(t[3]));
                }
            }
            {
                const u32 wda[8] = {lga2.x, lga2.y, lga2.z, lga2.w,
                                    lga3.x, lga3.y, lga3.z, lga3.w};
                const u32 wdb[8] = {lgb2.x, lgb2.y, lgb2.z, lgb2.w,
                                    lgb3.x, lgb3.y, lgb3.z, lgb3.w};
#pragma unroll
                for (int kk = 0; kk < 4; ++kk) {
                    s16x8 ka = *(const s16x8*)(KbL + bo + rb0 + (4 + kk) * 1024);
                    s16x8 kb = *(const s16x8*)(KbL + bo + rb1 + (4 + kk) * 1024);
                    f32x4 ci;
                    ci[0] = bflo(wda[kk * 2]);     ci[1] = bfhi(wda[kk * 2]);
                    ci[2] = bflo(wda[kk * 2 + 1]); ci[3] = bfhi(wda[kk * 2 + 1]);
                    f32x4 s = __builtin_amdgcn_mfma_f32_16x16x32_bf16(ka, qfa0, ci, 0, 0, 0);
                    s = __builtin_amdgcn_mfma_f32_16x16x32_bf16(kb, qfa1, s, 0, 0, 0);
                    f32x4 cj;
                    cj[0] = bflo(wdb[kk * 2]);     cj[1] = bfhi(wdb[kk * 2]);
                    cj[2] = bflo(wdb[kk * 2 + 1]); cj[3] = bfhi(wdb[kk * 2 + 1]);
                    f32x4 t = __builtin_amdgcn_mfma_f32_16x16x32_bf16(ka, qfb0, cj, 0, 0, 0);
                    t = __builtin_amdgcn_mfma_f32_16x16x32_bf16(kb, qfb1, t, 0, 0, 0);
                    PwA8[4 + kk][0] = pack_hi(__builtin_amdgcn_exp2f(s[0]),
                                              __builtin_amdgcn_exp2f(s[1]));
                    PwA8[4 + kk][1] = pack_hi(__builtin_amdgcn_exp2f(s[2]),
                                              __builtin_amdgcn_exp2f(s[3]));
                    PwB8[4 + kk][0] = pack_hi(__builtin_amdgcn_exp2f(t[0]),
                                              __builtin_amdgcn_exp2f(t[1]));
                    PwB8[4 + kk][1] = pack_hi(__builtin_amdgcn_exp2f(t[2]),
                                              __builtin_amdgcn_exp2f(t[3]));
                }
            }
            if (kt < 15) {
                lga0 = *(const uint4*)lgPa;
                lga1 = *(const uint4*)(lgPa + 8);
                lga2 = *(const uint4*)(lgPa + 1024);
                lga3 = *(const uint4*)(lgPa + 1032);
                lgb0 = *(const uint4*)lgPb;
                lgb1 = *(const uint4*)(lgPb + 8);
                lgb2 = *(const uint4*)(lgPb + 1024);
                lgb3 = *(const uint4*)(lgPb + 1032);
                lgPa += 2048; lgPb += 2048;
            }
#pragma unroll
            for (int kc = 0; kc < 4; ++kc) {
                union { u32 wrd[4]; s16x8 v; } pa, pb;
#pragma unroll
                for (int i = 0; i < 2; ++i) {
                    u32x2 r1 = __builtin_amdgcn_permlane32_swap(
                        PwA8[2 * kc][i], PwA8[2 * kc + 1][i], false, false);
                    u32x2 r2 = __builtin_amdgcn_permlane16_swap(
                        r1[0], r1[1], false, false);
                    pa.wrd[i]     = r2[0];
                    pa.wrd[2 + i] = r2[1];
                    u32x2 r3 = __builtin_amdgcn_permlane32_swap(
                        PwB8[2 * kc][i], PwB8[2 * kc + 1][i], false, false);
                    u32x2 r4 = __builtin_amdgcn_permlane16_swap(
                        r3[0], r3[1], false, false);
                    pb.wrd[i]     = r4[0];
                    pb.wrd[2 + i] = r4[1];
                }
                s16x8 pfa = pa.v, pfb = pb.v;
                laccA = __builtin_amdgcn_mfma_f32_16x16x32_bf16(pfa, ones, laccA, 0, 0, 0);
                laccB = __builtin_amdgcn_mfma_f32_16x16x32_bf16(pfb, ones, laccB, 0, 0, 0);
                const int vbb = ((kc & 1) ? rb1 : rb0) + (kc >> 1) * 4096 + bo;
#pragma unroll
                for (int dn = 0; dn < 4; ++dn) {
                    s16x8 vf = *(const s16x8*)(VbL + vbb + dn * 1024);
                    oA[dn] = __builtin_amdgcn_mfma_f32_16x16x32_bf16(
                        pfa, vf, oA[dn], 0, 0, 0);
                    oB[dn] = __builtin_amdgcn_mfma_f32_16x16x32_bf16(
                        pfb, vf, oB[dn], 0, 0, 0);
                }
            }
            __builtin_amdgcn_s_setprio(0);
        }
#pragma unroll
        for (int reg = 0; reg < 4; ++reg) {
            float invA = __builtin_amdgcn_rcpf(laccA[reg]);
            float invB = __builtin_amdgcn_rcpf(laccB[reg]);
            int trowA = b * 2048 + q0a + quad * 4 + reg;
            int trowB = b * 2048 + q0b + quad * 4 + reg;
#pragma unroll
            for (int dn = 0; dn < 4; ++dn) {
                Ob[(size_t)trowA * 512 + head * 64 + dn * 16 + l16] =
                    f2bf(oA[dn][reg] * invA);
                Ob[(size_t)trowB * 512 + head * 64 + dn * 16 + l16] =
                    f2bf(oB[dn][reg] * invB);
            }
        }
    }
    grid_barrier(bar + 128);

    // ---------------- Phase D: output projection (1 m64-tile/block) --------
    {
        u16* As = smem;
        u16* Bs = smem + 4096;
        const int n0 = (bid & 3) * 128;
        const int m0 = (bid >> 2) * 64;
        f32x4 acc[2][4];
        gemm_core_m64(Ob, cW + 786432, m0, n0, As, Bs, acc);
        const int wm = w & 1, wn = w >> 1;
#pragma unroll
        for (int nt = 0; nt < 4; ++nt) {
            int j = n0 + wn * 64 + nt * 16 + l16;
            float bj = bo[j];
#pragma unroll
            for (int mt = 0; mt < 2; ++mt) {
                int t = m0 + wm * 32 + mt * 16 + quad * 4;
#pragma unroll
                for (int reg = 0; reg < 4; ++reg)
                    out[(size_t)(t + reg) * 512 + j] = acc[mt][nt][reg] + bj;
            }
        }
    }
}

extern "C" void kernel_launch(void* const* d_in, const int* in_sizes, int n_in,
                              void* d_out, int out_size, void* d_ws, size_t ws_size,
                              hipStream_t stream)
{
    const float* Qin  = (const float*)d_in[0];
    const float* KVin = (const float*)d_in[1];
    const float* SC   = (const float*)d_in[2];
    const float* Wq   = (const float*)d_in[3];
    const float* bq   = (const float*)d_in[4];
    const float* Wk   = (const float*)d_in[5];
    const float* bk   = (const float*)d_in[6];
    const float* Wv   = (const float*)d_in[7];
    const float* bv   = (const float*)d_in[8];
    const float* gw   = (const float*)d_in[9];
    const float* gb   = (const float*)d_in[10];
    const float* Wo   = (const float*)d_in[11];
    const float* bo   = (const float*)d_in[12];
    float* outp = (float*)d_out;
    u16* ws16 = (u16*)d_ws;

    // Barrier counters live past the 86 MB data region (u16 offset 42,991,616).
    u32* bar = (u32*)((char*)d_ws + 85983232);
    hipMemsetAsync(bar, 0, 1024, stream);   // zero 3 barrier slots (stream-ordered)

    hipLaunchKernelGGL(mega_kernel, dim3(512), dim3(256), 0, stream,
                       Qin, KVin, SC, Wq, bq, Wk, bk, Wv, bv,
                       gw, gb, Wo, bo, outp, ws16, bar);
}